// Round 5
// baseline (524.896 us; speedup 1.0000x reference)
//
#include <hip/hip_runtime.h>
#include <hip/hip_bf16.h>
#include <math.h>

typedef float  f32x4  __attribute__((ext_vector_type(4)));
typedef short  bf16x4 __attribute__((ext_vector_type(4)));
typedef __bf16 bfv4   __attribute__((ext_vector_type(4)));

#define B_    16
#define S_    4096
#define D_    256
#define CK_   16                 // chunk length
#define NC_   (S_ / CK_)         // 256 chunks
#define NP_   (NC_ / 2)          // 128 fused pairs (32-row superchunks)
#define PBLOB_ 1664              // 512 Ta + 512 Tb + 512 Gx (bf16) + 64 ca + 64 cb (f32)

// ---------------- helpers
__device__ __forceinline__ f32x4 mfma_bf16(bf16x4 a, bf16x4 b, f32x4 c) {
#if defined(__has_builtin) && __has_builtin(__builtin_amdgcn_mfma_f32_16x16x16bf16_1k)
    return __builtin_amdgcn_mfma_f32_16x16x16bf16_1k(a, b, c, 0, 0, 0);
#else
    f32x4 d;
    asm("v_mfma_f32_16x16x16_bf16 %0, %1, %2, %3" : "=v"(d) : "v"(a), "v"(b), "v"(c));
    return d;
#endif
}
__device__ __forceinline__ bf16x4 pk4(f32x4 v) {
    bfv4 h;
    h[0] = (__bf16)v[0]; h[1] = (__bf16)v[1]; h[2] = (__bf16)v[2]; h[3] = (__bf16)v[3];
    return __builtin_bit_cast(bf16x4, h);
}
__device__ __forceinline__ f32x4 up4(bf16x4 h) {
    f32x4 r;
    r[0] = __uint_as_float(((unsigned)(unsigned short)h[0]) << 16);
    r[1] = __uint_as_float(((unsigned)(unsigned short)h[1]) << 16);
    r[2] = __uint_as_float(((unsigned)(unsigned short)h[2]) << 16);
    r[3] = __uint_as_float(((unsigned)(unsigned short)h[3]) << 16);
    return r;
}

// ---------------- prepass: one 64-thread wave per (b, pair). (R1/R3-verified, unchanged)
__global__ __launch_bounds__(64) void ldm_prep(
    const float* __restrict__ x,
    const float* __restrict__ eta_raw,
    const float* __restrict__ alpha_raw,
    unsigned char* __restrict__ blob)
{
    const int lane = threadIdx.x;
    const int b = blockIdx.x >> 7;            // NP_ = 128
    const int p = blockIdx.x & (NP_ - 1);
    const int l15 = lane & 15;
    const int q   = lane >> 4;

    __shared__ float Ga[256], Gb[256], Gxs[256];
    __shared__ float csh[32];
    __shared__ float Ts[2][256];

    const float* xa = x + ((size_t)b * S_ + (size_t)p * 32 + l15) * D_ + q * 4;
    const float* xc = xa + 16 * D_;           // chunk b rows

    const f32x4 z = {0,0,0,0};
    f32x4 ga1=z, ga2=z, ga3=z, gb1=z, gb2=z, gb3=z, gx1=z, gx2=z, gx3=z;
    #pragma unroll 4
    for (int kb = 0; kb < 16; ++kb) {
        f32x4 va = *(const f32x4*)(xa + kb * 16);
        f32x4 vb = *(const f32x4*)(xc + kb * 16);
        bf16x4 ha = pk4(va), la = pk4(va - up4(ha));
        bf16x4 hb = pk4(vb), lb = pk4(vb - up4(hb));
        ga1 = mfma_bf16(ha, ha, ga1);
        ga2 = mfma_bf16(ha, la, ga2);
        ga3 = mfma_bf16(la, ha, ga3);
        gb1 = mfma_bf16(hb, hb, gb1);
        gb2 = mfma_bf16(hb, lb, gb2);
        gb3 = mfma_bf16(lb, hb, gb3);
        gx1 = mfma_bf16(hb, ha, gx1);         // Gx[t_b][t_a] = x_b . x_a
        gx2 = mfma_bf16(hb, la, gx2);
        gx3 = mfma_bf16(lb, ha, gx3);
    }
    f32x4 ga = (ga1 + ga2) + ga3;             // C layout: lane holds G[q*4+r][l15]
    f32x4 gb = (gb1 + gb2) + gb3;
    f32x4 gx = (gx1 + gx2) + gx3;
    *(f32x4*)(&Ga[l15 * 16 + q * 4]) = ga;    // symmetric: transposed store ok
    *(f32x4*)(&Gb[l15 * 16 + q * 4]) = gb;
    #pragma unroll
    for (int r = 0; r < 4; ++r) Gxs[(q * 4 + r) * 16 + l15] = gx[r];
    __syncthreads();

    const float eta   = 0.2f / (1.0f + expf(-eta_raw[0]));
    const float alpha = 0.5f + 0.5f / (1.0f + expf(-alpha_raw[0]));
    if (lane < 32) {
        const float* G = (lane < 16) ? Ga : Gb;
        float gtt = G[l15 * 17];
        float n   = fmaxf(sqrtf(gtt), 1e-6f);
        float inv = 1.0f / n;
        csh[lane] = eta * (1.0f - inv) * inv / alpha;
    }
    __syncthreads();

    if (lane < 32) {                          // column-parallel forward substitution x2
        const int j = l15;
        const float* G  = (lane < 16) ? Ga : Gb;
        const float* cp = (lane < 16) ? csh : csh + 16;
        float cr[16];
        #pragma unroll
        for (int k = 0; k < 16; ++k) cr[k] = cp[k];
        float Tcol[16];
        Tcol[0] = 0.f;
        #pragma unroll
        for (int t = 1; t < 16; ++t) {
            float acc = cr[j] * G[t * 16 + j];
            #pragma unroll
            for (int k = 1; k < 15; ++k)
                if (k < t) acc += cr[k] * G[t * 16 + k] * Tcol[k];
            Tcol[t] = (t > j) ? acc : 0.f;
        }
        float* Tsj = Ts[lane >> 4];
        #pragma unroll
        for (int t = 0; t < 16; ++t) Tsj[t * 16 + j] = Tcol[t];
    }
    __syncthreads();

    unsigned char* bp = blob + (size_t)(b * NP_ + p) * PBLOB_;
    const int idx = l15 * 16 + q * 4;
    *(bf16x4*)(bp + idx * 2)        = pk4(*(const f32x4*)(&Ts[0][idx]));
    *(bf16x4*)(bp + 512 + idx * 2)  = pk4(*(const f32x4*)(&Ts[1][idx]));
    *(bf16x4*)(bp + 1024 + idx * 2) = pk4(*(const f32x4*)(&Gxs[idx]));
    if (lane < 32) ((float*)(bp + 1536))[lane] = csh[lane];
}

// ---------------- main scan: ONE 64-thread wave per (batch, rowblk).
// The wave owns the full 16x256 master block (16 f32x4 C-frags = 64 VGPR).
// Zero barriers, zero LDS: retrieval = 16 wave-local MFMAs (4 indep chains),
// in-pair fixup via Ta/Gx/Tb (R3-verified algebra), transpose via identity
// MFMA, rank-32 update = 32 MFMAs. 256 independent waves = 1 per CU.
__global__ __launch_bounds__(64, 1) void ldm_main(
    const float* __restrict__ x,
    const float* __restrict__ Minit,
    const float* __restrict__ alpha_raw,
    const unsigned char* __restrict__ blob,
    float* __restrict__ out)
{
    const int lane   = threadIdx.x;
    const int batch  = blockIdx.x >> 4;
    const int rowblk = blockIdx.x & 15;
    const int l15    = lane & 15;
    const int q      = lane >> 4;

    const float alpha = 0.5f + 0.5f / (1.0f + expf(-alpha_raw[0]));
    const float a2 = alpha * alpha, a4 = a2 * a2, a8 = a4 * a4, a16 = a8 * a8;
    const float a32 = a16 * a16;
    const float aq = (q == 0) ? 1.f : (q == 1) ? a4 : (q == 2) ? a8 : a8 * a4;
    const f32x4 apowA = { aq, aq * alpha, aq * a2, aq * a2 * alpha };
    const f32x4 apowB = apowA * a16;

    // identity B-fragment for transpose MFMA
    const int s = l15 - (q << 2);
    bf16x4 IB;
    IB[0] = (s == 0) ? (short)0x3F80 : (short)0;
    IB[1] = (s == 1) ? (short)0x3F80 : (short)0;
    IB[2] = (s == 2) ? (short)0x3F80 : (short)0;
    IB[3] = (s == 3) ? (short)0x3F80 : (short)0;

    const int mrow = rowblk * 16 + l15;
    f32x4 master[16];                         // full 16x256 block, C-frag per 16-col blk
    #pragma unroll
    for (int cb = 0; cb < 16; ++cb)
        master[cb] = *(const f32x4*)(Minit + (size_t)mrow * D_ + cb * 16 + q * 4);

    const float* xbb = x + (size_t)batch * S_ * D_;
    const unsigned char* bb0 = blob + (size_t)batch * NP_ * PBLOB_;
    const int tfoff = (l15 * 16 + q * 4) * 2;

    const float* xr = xbb + (size_t)l15 * D_ + q * 4;   // row l15, col q*4
    const float* xptr;
    const unsigned char* bptr;
    float* outpj = out + (size_t)batch * S_ * D_ + rowblk * 16 + l15
                 + (size_t)q * 4 * D_;                  // chunk-a row base, pair 0

    struct BlobT { bf16x4 Ta, Tb, Gx; f32x4 ca, cb; };
    BlobT bA, bB;
    bf16x4 XA[32], XB[32];     // bf16 A-frags: [0..15]=chunk a, [16..31]=chunk b
    f32x4  Xfa[16], Xfb[16];   // next-pair f32 in flight
    const f32x4 zz = {0,0,0,0};

    {   // ---------------- prologue: pair 0
        #pragma unroll
        for (int cb = 0; cb < 16; ++cb) {
            Xfa[cb] = *(const f32x4*)(xr + cb * 16);
            Xfb[cb] = *(const f32x4*)(xr + 16 * D_ + cb * 16);
        }
        #pragma unroll
        for (int cb = 0; cb < 16; ++cb) {
            XA[cb]      = pk4(Xfa[cb]);
            XA[16 + cb] = pk4(Xfb[cb]);
        }
        bA.Ta = *(const bf16x4*)(bb0 + tfoff);
        bA.Tb = *(const bf16x4*)(bb0 + 512 + tfoff);
        bA.Gx = *(const bf16x4*)(bb0 + 1024 + tfoff);
        bA.ca = *(const f32x4*)(bb0 + 1536 + q * 16);
        bA.cb = *(const f32x4*)(bb0 + 1600 + q * 16);
        xptr = xr + 32 * D_;                  // -> X(1)
        bptr = bb0 + PBLOB_;                  // -> blob(1)
    }

    auto body = [&](int j, bf16x4 (&Xc)[32], bf16x4 (&Xn)[32], BlobT& bc, BlobT& bn) {
        // 1. prefetch pair j+1 (f32 X + blob); waitcnt lands at step 6
        #pragma unroll
        for (int cb = 0; cb < 16; ++cb) {
            Xfa[cb] = *(const f32x4*)(xptr + cb * 16);
            Xfb[cb] = *(const f32x4*)(xptr + 16 * D_ + cb * 16);
        }
        bn.Ta = *(const bf16x4*)(bptr + tfoff);
        bn.Tb = *(const bf16x4*)(bptr + 512 + tfoff);
        bn.Gx = *(const bf16x4*)(bptr + 1024 + tfoff);
        bn.ca = *(const f32x4*)(bptr + 1536 + q * 16);
        bn.cb = *(const f32x4*)(bptr + 1600 + q * 16);
        if (j < NP_ - 2) { xptr += 32 * D_; bptr += PBLOB_; }

        // 2. master -> bf16 B-frags
        bf16x4 mf[16];
        #pragma unroll
        for (int cb = 0; cb < 16; ++cb) mf[cb] = pk4(master[cb]);

        // 3. retrieval bb = X . M^T over all 256 cols: 4 independent C-chains of 8
        f32x4 pa0 = zz, pa1 = zz, pb0 = zz, pb1 = zz;
        #pragma unroll
        for (int cb = 0; cb < 8; ++cb) {
            pa0 = mfma_bf16(Xc[cb],      mf[cb],     pa0);
            pa1 = mfma_bf16(Xc[8 + cb],  mf[8 + cb], pa1);
            pb0 = mfma_bf16(Xc[16 + cb], mf[cb],     pb0);
            pb1 = mfma_bf16(Xc[24 + cb], mf[8 + cb], pb1);
        }
        f32x4 bba = pa0 + pa1;
        f32x4 bbb = pb0 + pb1;

        // 4. fixup chain (R3-verified): d_a = (I+T_a)*bb_a; cross; d_b
        f32x4 da = mfma_bf16(bc.Ta, pk4(bba), bba);
        #pragma unroll
        for (int r = 0; r < 4; ++r) outpj[r * D_] = da[r] * apowA[r];
        bf16x4 ea = pk4(da * bc.ca);
        f32x4 bbc = mfma_bf16(bc.Gx, ea, bbb);
        f32x4 db = mfma_bf16(bc.Tb, pk4(bbc), bbc);
        #pragma unroll
        for (int r = 0; r < 4; ++r) outpj[(16 + r) * D_] = db[r] * apowB[r];
        bf16x4 eb = pk4(db * bc.cb);

        // 5. transpose (identity MFMA) + rank-32 update, all 16 col-blocks
        #pragma unroll
        for (int cb = 0; cb < 16; ++cb) {
            bf16x4 ta = pk4(mfma_bf16(Xc[cb],      IB, zz));
            bf16x4 tb = pk4(mfma_bf16(Xc[16 + cb], IB, zz));
            f32x4 m = mfma_bf16(ta, ea, master[cb]);
            master[cb] = mfma_bf16(tb, eb, m) * a32;
        }

        // 6. convert next pair to bf16 (load->use distance ~ one full body)
        #pragma unroll
        for (int cb = 0; cb < 16; ++cb) {
            Xn[cb]      = pk4(Xfa[cb]);
            Xn[16 + cb] = pk4(Xfb[cb]);
        }
        outpj += 32 * D_;
    };

    for (int j = 0; j < NP_; j += 2) {
        body(j,     XA, XB, bA, bB);
        body(j + 1, XB, XA, bB, bA);
    }

    // M_final -> second output region [B, D, D]
    float* Mout = out + (size_t)B_ * S_ * D_
                + ((size_t)batch * D_ + mrow) * D_;
    #pragma unroll
    for (int cb = 0; cb < 16; ++cb)
        *(f32x4*)(Mout + cb * 16 + q * 4) = master[cb];
}

extern "C" void kernel_launch(void* const* d_in, const int* in_sizes, int n_in,
                              void* d_out, int out_size, void* d_ws, size_t ws_size,
                              hipStream_t stream) {
    const float* x         = (const float*)d_in[0];
    const float* Minit     = (const float*)d_in[1];
    const float* eta_raw   = (const float*)d_in[2];
    const float* alpha_raw = (const float*)d_in[3];
    float* out = (float*)d_out;
    unsigned char* blob = (unsigned char*)d_ws;   // B_*NP_*1664 = 3.4 MB

    hipLaunchKernelGGL(ldm_prep, dim3(B_ * NP_), dim3(64), 0, stream,
                       x, eta_raw, alpha_raw, blob);
    hipLaunchKernelGGL(ldm_main, dim3(B_ * 16), dim3(64), 0, stream,
                       x, Minit, alpha_raw, blob, out);
}

// Round 6
// 280.449 us; speedup vs baseline: 1.8716x; 1.8716x over previous
//
#include <hip/hip_runtime.h>
#include <hip/hip_bf16.h>
#include <math.h>

typedef float  f32x4  __attribute__((ext_vector_type(4)));
typedef short  bf16x4 __attribute__((ext_vector_type(4)));
typedef __bf16 bfv4   __attribute__((ext_vector_type(4)));

#define B_    16
#define S_    4096
#define D_    256
#define CK_   16                 // chunk length
#define NC_   (S_ / CK_)         // 256 chunks
#define NP_   (NC_ / 2)          // 128 fused pairs (32-row superchunks)
#define PBLOB_ 1664              // 512 Ta + 512 Tb + 512 Gx (bf16) + 64 ca + 64 cb (f32)
#define W_    4                  // waves per main block (column split, 64 cols each)

// ---------------- helpers
__device__ __forceinline__ f32x4 mfma_bf16(bf16x4 a, bf16x4 b, f32x4 c) {
#if defined(__has_builtin) && __has_builtin(__builtin_amdgcn_mfma_f32_16x16x16bf16_1k)
    return __builtin_amdgcn_mfma_f32_16x16x16bf16_1k(a, b, c, 0, 0, 0);
#else
    f32x4 d;
    asm("v_mfma_f32_16x16x16_bf16 %0, %1, %2, %3" : "=v"(d) : "v"(a), "v"(b), "v"(c));
    return d;
#endif
}
__device__ __forceinline__ bf16x4 pk4(f32x4 v) {
    bfv4 h;
    h[0] = (__bf16)v[0]; h[1] = (__bf16)v[1]; h[2] = (__bf16)v[2]; h[3] = (__bf16)v[3];
    return __builtin_bit_cast(bf16x4, h);
}
__device__ __forceinline__ f32x4 up4(bf16x4 h) {
    f32x4 r;
    r[0] = __uint_as_float(((unsigned)(unsigned short)h[0]) << 16);
    r[1] = __uint_as_float(((unsigned)(unsigned short)h[1]) << 16);
    r[2] = __uint_as_float(((unsigned)(unsigned short)h[2]) << 16);
    r[3] = __uint_as_float(((unsigned)(unsigned short)h[3]) << 16);
    return r;
}

// ---------------- prepass: one 64-thread wave per (b, pair). (R1/R3-verified, unchanged)
__global__ __launch_bounds__(64) void ldm_prep(
    const float* __restrict__ x,
    const float* __restrict__ eta_raw,
    const float* __restrict__ alpha_raw,
    unsigned char* __restrict__ blob)
{
    const int lane = threadIdx.x;
    const int b = blockIdx.x >> 7;            // NP_ = 128
    const int p = blockIdx.x & (NP_ - 1);
    const int l15 = lane & 15;
    const int q   = lane >> 4;

    __shared__ float Ga[256], Gb[256], Gxs[256];
    __shared__ float csh[32];
    __shared__ float Ts[2][256];

    const float* xa = x + ((size_t)b * S_ + (size_t)p * 32 + l15) * D_ + q * 4;
    const float* xc = xa + 16 * D_;           // chunk b rows

    const f32x4 z = {0,0,0,0};
    f32x4 ga1=z, ga2=z, ga3=z, gb1=z, gb2=z, gb3=z, gx1=z, gx2=z, gx3=z;
    #pragma unroll 4
    for (int kb = 0; kb < 16; ++kb) {
        f32x4 va = *(const f32x4*)(xa + kb * 16);
        f32x4 vb = *(const f32x4*)(xc + kb * 16);
        bf16x4 ha = pk4(va), la = pk4(va - up4(ha));
        bf16x4 hb = pk4(vb), lb = pk4(vb - up4(hb));
        ga1 = mfma_bf16(ha, ha, ga1);
        ga2 = mfma_bf16(ha, la, ga2);
        ga3 = mfma_bf16(la, ha, ga3);
        gb1 = mfma_bf16(hb, hb, gb1);
        gb2 = mfma_bf16(hb, lb, gb2);
        gb3 = mfma_bf16(lb, hb, gb3);
        gx1 = mfma_bf16(hb, ha, gx1);         // Gx[t_b][t_a] = x_b . x_a
        gx2 = mfma_bf16(hb, la, gx2);
        gx3 = mfma_bf16(lb, ha, gx3);
    }
    f32x4 ga = (ga1 + ga2) + ga3;             // C layout: lane holds G[q*4+r][l15]
    f32x4 gb = (gb1 + gb2) + gb3;
    f32x4 gx = (gx1 + gx2) + gx3;
    *(f32x4*)(&Ga[l15 * 16 + q * 4]) = ga;    // symmetric: transposed store ok
    *(f32x4*)(&Gb[l15 * 16 + q * 4]) = gb;
    #pragma unroll
    for (int r = 0; r < 4; ++r) Gxs[(q * 4 + r) * 16 + l15] = gx[r];
    __syncthreads();

    const float eta   = 0.2f / (1.0f + expf(-eta_raw[0]));
    const float alpha = 0.5f + 0.5f / (1.0f + expf(-alpha_raw[0]));
    if (lane < 32) {
        const float* G = (lane < 16) ? Ga : Gb;
        float gtt = G[l15 * 17];
        float n   = fmaxf(sqrtf(gtt), 1e-6f);
        float inv = 1.0f / n;
        csh[lane] = eta * (1.0f - inv) * inv / alpha;
    }
    __syncthreads();

    if (lane < 32) {                          // column-parallel forward substitution x2
        const int j = l15;
        const float* G  = (lane < 16) ? Ga : Gb;
        const float* cp = (lane < 16) ? csh : csh + 16;
        float cr[16];
        #pragma unroll
        for (int k = 0; k < 16; ++k) cr[k] = cp[k];
        float Tcol[16];
        Tcol[0] = 0.f;
        #pragma unroll
        for (int t = 1; t < 16; ++t) {
            float acc = cr[j] * G[t * 16 + j];
            #pragma unroll
            for (int k = 1; k < 15; ++k)
                if (k < t) acc += cr[k] * G[t * 16 + k] * Tcol[k];
            Tcol[t] = (t > j) ? acc : 0.f;
        }
        float* Tsj = Ts[lane >> 4];
        #pragma unroll
        for (int t = 0; t < 16; ++t) Tsj[t * 16 + j] = Tcol[t];
    }
    __syncthreads();

    unsigned char* bp = blob + (size_t)(b * NP_ + p) * PBLOB_;
    const int idx = l15 * 16 + q * 4;
    *(bf16x4*)(bp + idx * 2)        = pk4(*(const f32x4*)(&Ts[0][idx]));
    *(bf16x4*)(bp + 512 + idx * 2)  = pk4(*(const f32x4*)(&Ts[1][idx]));
    *(bf16x4*)(bp + 1024 + idx * 2) = pk4(*(const f32x4*)(&Gxs[idx]));
    if (lane < 32) ((float*)(bp + 1536))[lane] = csh[lane];
}

// ---------------- main scan: one 256-thread block (4 waves) per (batch, rowblk).
// Wave w owns 64 cols [w*64, w*64+64) of the 16-row master block: master = 4
// f32x4 C-frags. Per pair: 8 retrieval MFMAs (partials over own cols) ->
// ds_write 2 -> ONE __syncthreads -> each wave reads all 4x2 partials and sums
// (no designated-reducer round trip, no second barrier) -> R3-verified fixup
// (Ta, Gx cross-correction, Tb) -> rank-32 update on own cols. Parity-indexed
// LDS makes the single barrier race-free. 1 wave/SIMD with ~150 VGPR of
// headroom for the scheduler to hide chain latency.
__global__ __launch_bounds__(256, 1) void ldm_main(
    const float* __restrict__ x,
    const float* __restrict__ Minit,
    const float* __restrict__ alpha_raw,
    const unsigned char* __restrict__ blob,
    float* __restrict__ out)
{
    const int tid    = threadIdx.x;
    const int lane   = tid & 63;
    const int w      = __builtin_amdgcn_readfirstlane(tid >> 6); // 0..3
    const int batch  = blockIdx.x >> 4;
    const int rowblk = blockIdx.x & 15;
    const int l15    = lane & 15;
    const int q      = lane >> 4;
    const int col0   = w * 64;                // wave's 64-col slice

    __shared__ f32x4 parts[2][W_][2][64];     // [parity][wave][chunk][lane] = 16 KB

    const float alpha = 0.5f + 0.5f / (1.0f + expf(-alpha_raw[0]));
    const float a2 = alpha * alpha, a4 = a2 * a2, a8 = a4 * a4, a16 = a8 * a8;
    const float a32 = a16 * a16;
    const float aq = (q == 0) ? 1.f : (q == 1) ? a4 : (q == 2) ? a8 : a8 * a4;
    const f32x4 apowA = { aq, aq * alpha, aq * a2, aq * a2 * alpha };
    const f32x4 apowB = apowA * a16;

    // identity B-fragment for transpose MFMA
    const int s = l15 - (q << 2);
    bf16x4 IB;
    IB[0] = (s == 0) ? (short)0x3F80 : (short)0;
    IB[1] = (s == 1) ? (short)0x3F80 : (short)0;
    IB[2] = (s == 2) ? (short)0x3F80 : (short)0;
    IB[3] = (s == 3) ? (short)0x3F80 : (short)0;

    const int mrow = rowblk * 16 + l15;
    f32x4 master[4];                          // 16 rows x own 64 cols
    #pragma unroll
    for (int cb = 0; cb < 4; ++cb)
        master[cb] = *(const f32x4*)(Minit + (size_t)mrow * D_ + col0 + cb * 16 + q * 4);

    const float* xbb = x + (size_t)batch * S_ * D_;
    const unsigned char* bb0 = blob + (size_t)batch * NP_ * PBLOB_;
    const int tfoff = (l15 * 16 + q * 4) * 2;

    const float* xr = xbb + (size_t)l15 * D_ + col0 + q * 4;  // row l15, own col
    const float* xptr;
    const unsigned char* bptr;
    float* outpj = out + (size_t)batch * S_ * D_ + rowblk * 16 + l15
                 + (size_t)q * 4 * D_;        // chunk-a row base, pair 0

    struct BlobT { bf16x4 Ta, Tb, Gx; f32x4 ca, cb; };
    BlobT bA, bB;
    bf16x4 XA[8], XB[8];       // bf16 A-frags: [0..3]=chunk a, [4..7]=chunk b
    f32x4  Xf[8];              // next-pair f32 in flight (32 VGPR)
    const f32x4 zz = {0,0,0,0};

    {   // ---------------- prologue: pair 0
        #pragma unroll
        for (int cb = 0; cb < 4; ++cb) {
            Xf[cb]     = *(const f32x4*)(xr + cb * 16);
            Xf[4 + cb] = *(const f32x4*)(xr + 16 * D_ + cb * 16);
        }
        #pragma unroll
        for (int i = 0; i < 8; ++i) XA[i] = pk4(Xf[i]);
        bA.Ta = *(const bf16x4*)(bb0 + tfoff);
        bA.Tb = *(const bf16x4*)(bb0 + 512 + tfoff);
        bA.Gx = *(const bf16x4*)(bb0 + 1024 + tfoff);
        bA.ca = *(const f32x4*)(bb0 + 1536 + q * 16);
        bA.cb = *(const f32x4*)(bb0 + 1600 + q * 16);
        xptr = xr + 32 * D_;                  // -> X(1)
        bptr = bb0 + PBLOB_;                  // -> blob(1)
    }

    auto body = [&](int j, bf16x4 (&Xc)[8], bf16x4 (&Xn)[8], BlobT& bc, BlobT& bn) {
        const int par = j & 1;
        // prefetch pair j+1 (f32 X + blob); converted at body end
        #pragma unroll
        for (int cb = 0; cb < 4; ++cb) {
            Xf[cb]     = *(const f32x4*)(xptr + cb * 16);
            Xf[4 + cb] = *(const f32x4*)(xptr + 16 * D_ + cb * 16);
        }
        bn.Ta = *(const bf16x4*)(bptr + tfoff);
        bn.Tb = *(const bf16x4*)(bptr + 512 + tfoff);
        bn.Gx = *(const bf16x4*)(bptr + 1024 + tfoff);
        bn.ca = *(const f32x4*)(bptr + 1536 + q * 16);
        bn.cb = *(const f32x4*)(bptr + 1600 + q * 16);
        if (j < NP_ - 2) { xptr += 32 * D_; bptr += PBLOB_; }

        // retrieval partials over own 64 cols (4-deep C-chains, a/b independent)
        bf16x4 mf[4];
        #pragma unroll
        for (int cb = 0; cb < 4; ++cb) mf[cb] = pk4(master[cb]);
        f32x4 acca = zz, accb = zz;
        #pragma unroll
        for (int cb = 0; cb < 4; ++cb) {
            acca = mfma_bf16(Xc[cb],     mf[cb], acca);
            accb = mfma_bf16(Xc[4 + cb], mf[cb], accb);
        }
        parts[par][w][0][lane] = acca;
        parts[par][w][1][lane] = accb;

        // transpose frags (independent of master/reduce; fills pre-barrier)
        bf16x4 ta[4], tb[4];
        #pragma unroll
        for (int cb = 0; cb < 4; ++cb) {
            ta[cb] = pk4(mfma_bf16(Xc[cb],     IB, zz));
            tb[cb] = pk4(mfma_bf16(Xc[4 + cb], IB, zz));
        }
        __syncthreads();                      // the ONE barrier per pair

        // direct 4-partial reduce (every wave reads all partials)
        f32x4 pa0 = parts[par][0][0][lane], pa1 = parts[par][1][0][lane];
        f32x4 pa2 = parts[par][2][0][lane], pa3 = parts[par][3][0][lane];
        f32x4 pb0 = parts[par][0][1][lane], pb1 = parts[par][1][1][lane];
        f32x4 pb2 = parts[par][2][1][lane], pb3 = parts[par][3][1][lane];
        f32x4 bba = (pa0 + pa1) + (pa2 + pa3);
        f32x4 bbb = (pb0 + pb1) + (pb2 + pb3);

        // chunk a fixup: d_a = (I+T_a)*bb_a
        f32x4 da = mfma_bf16(bc.Ta, pk4(bba), bba);
        if (w == 2) {
            #pragma unroll
            for (int r = 0; r < 4; ++r) outpj[r * D_] = da[r] * apowA[r];
        }
        bf16x4 ea = pk4(da * bc.ca);
        // chunk b in-pair cross-correction + fixup
        f32x4 bb2 = mfma_bf16(bc.Gx, ea, bbb);
        f32x4 db = mfma_bf16(bc.Tb, pk4(bb2), bb2);
        if (w == 3) {
            #pragma unroll
            for (int r = 0; r < 4; ++r) outpj[(16 + r) * D_] = db[r] * apowB[r];
        }
        bf16x4 eb = pk4(db * bc.cb);

        // rank-32 update on own cols, then *alpha^32
        #pragma unroll
        for (int cb = 0; cb < 4; ++cb) {
            f32x4 m = mfma_bf16(ta[cb], ea, master[cb]);
            master[cb] = mfma_bf16(tb[cb], eb, m) * a32;
        }

        // convert next pair to bf16 (load->use distance ~ one full body)
        #pragma unroll
        for (int i = 0; i < 8; ++i) Xn[i] = pk4(Xf[i]);
        outpj += 32 * D_;
    };

    for (int j = 0; j < NP_; j += 2) {
        body(j,     XA, XB, bA, bB);
        body(j + 1, XB, XA, bB, bA);
    }

    // M_final -> second output region [B, D, D]
    float* Mout = out + (size_t)B_ * S_ * D_
                + ((size_t)batch * D_ + mrow) * D_;
    #pragma unroll
    for (int cb = 0; cb < 4; ++cb)
        *(f32x4*)(Mout + col0 + cb * 16 + q * 4) = master[cb];
}

extern "C" void kernel_launch(void* const* d_in, const int* in_sizes, int n_in,
                              void* d_out, int out_size, void* d_ws, size_t ws_size,
                              hipStream_t stream) {
    const float* x         = (const float*)d_in[0];
    const float* Minit     = (const float*)d_in[1];
    const float* eta_raw   = (const float*)d_in[2];
    const float* alpha_raw = (const float*)d_in[3];
    float* out = (float*)d_out;
    unsigned char* blob = (unsigned char*)d_ws;   // B_*NP_*1664 = 3.4 MB

    hipLaunchKernelGGL(ldm_prep, dim3(B_ * NP_), dim3(64), 0, stream,
                       x, eta_raw, alpha_raw, blob);
    hipLaunchKernelGGL(ldm_main, dim3(B_ * 16), dim3(256), 0, stream,
                       x, Minit, alpha_raw, blob, out);
}